// Round 22
// baseline (1120.643 us; speedup 1.0000x reference)
//
#include <hip/hip_runtime.h>
#include <hip/hip_bf16.h>
#include <cstdint>
#include <math.h>

typedef __attribute__((ext_vector_type(4))) float f32x4;
typedef __attribute__((ext_vector_type(8))) __bf16 bf16x8;

__device__ __forceinline__ unsigned short f2bf(float f) {
    union { float f; unsigned u; } v; v.f = f;
    unsigned u = v.u + 0x7fffu + ((v.u >> 16) & 1u);
    return (unsigned short)(u >> 16);
}

__device__ __forceinline__ float gelu_tanh(float x) {
    float x3 = x * x * x;
    float t = tanhf(0.7978845608028654f * (x + 0.044715f * x3));
    return 0.5f * x * (1.0f + t);
}

__device__ __forceinline__ void gload_lds16(const void* g, void* l) {
    __builtin_amdgcn_global_load_lds(
        (__attribute__((address_space(1))) void*)(uintptr_t)g,
        (__attribute__((address_space(3))) void*)(unsigned)(uintptr_t)l,
        16, 0, 0);
}

// ---------------- fused bias-add + residual + LayerNorm ----------------
__global__ __launch_bounds__(256)
void fused_add_ln(const float* __restrict__ in, const float* __restrict__ res,
                  const float* __restrict__ bias, const float* __restrict__ nw,
                  const float* __restrict__ nb, float* __restrict__ resadd,
                  unsigned short* __restrict__ lnout, int H) {
    const int row = blockIdx.x;
    const int tid = threadIdx.x;
    const size_t base = (size_t)row * H;
    float v[16];
    float s = 0.f, ss = 0.f;
#pragma unroll
    for (int i = 0; i < 4; ++i) {
        int idx = (i * 256 + tid) * 4;
        float4 a = *(const float4*)(in + base + idx);
        float4 b = *(const float4*)(res + base + idx);
        float4 c = *(const float4*)(bias + idx);
        float x0 = a.x + b.x + c.x, x1 = a.y + b.y + c.y;
        float x2 = a.z + b.z + c.z, x3 = a.w + b.w + c.w;
        v[i * 4 + 0] = x0; v[i * 4 + 1] = x1; v[i * 4 + 2] = x2; v[i * 4 + 3] = x3;
        s += x0 + x1 + x2 + x3;
        ss += x0 * x0 + x1 * x1 + x2 * x2 + x3 * x3;
    }
#pragma unroll
    for (int off = 32; off > 0; off >>= 1) {
        s += __shfl_down(s, off);
        ss += __shfl_down(ss, off);
    }
    __shared__ float red[8];
    const int w = tid >> 6;
    if ((tid & 63) == 0) { red[w] = s; red[4 + w] = ss; }
    __syncthreads();
    s = red[0] + red[1] + red[2] + red[3];
    ss = red[4] + red[5] + red[6] + red[7];
    const float mean = s / H;
    const float var = ss / H - mean * mean;
    const float rstd = rsqrtf(var + 1e-12f);
#pragma unroll
    for (int i = 0; i < 4; ++i) {
        int idx = (i * 256 + tid) * 4;
        float4 wv = *(const float4*)(nw + idx);
        float4 bv = *(const float4*)(nb + idx);
        float4 r;
        r.x = v[i * 4 + 0]; r.y = v[i * 4 + 1]; r.z = v[i * 4 + 2]; r.w = v[i * 4 + 3];
        *(float4*)(resadd + base + idx) = r;
        ushort4 o;
        o.x = f2bf((r.x - mean) * rstd * wv.x + bv.x);
        o.y = f2bf((r.y - mean) * rstd * wv.y + bv.y);
        o.z = f2bf((r.z - mean) * rstd * wv.z + bv.z);
        o.w = f2bf((r.w - mean) * rstd * wv.w + bv.w);
        *(ushort4*)(lnout + base + idx) = o;
    }
}

// ---------------- fp32 -> bf16 weight cast ----------------
__global__ __launch_bounds__(256)
void cast_w(const float* __restrict__ w, unsigned short* __restrict__ o, long long n4) {
    long long i = (long long)blockIdx.x * 256 + threadIdx.x;
    if (i >= n4) return;
    float4 f = *(const float4*)(w + i * 4);
    ushort4 u;
    u.x = f2bf(f.x); u.y = f2bf(f.y); u.z = f2bf(f.z); u.w = f2bf(f.w);
    *(ushort4*)(o + i * 4) = u;
}

// ---- 256x256 bf16 GEMM, C = A*B^T: faithful m201-style 8-phase ----------
// {RD; STAGE; [gates]; BAR; lgkm(0); MFMA; BAR} — the one untried point:
// reads drain ACROSS the barrier wait; stage issued pre-BAR; second
// barrier phase-locks MFMA clusters across waves. 512 thr = 8 waves
// (2M x 4N), per-wave 128x64. LDS 128 KiB, slot = tile&1.
// Gate audit (counting from gate program position — R20 lesson):
//  p4 gate AFTER p4's stage: in-flight = {prev-p7,prev-p8,p1,p2,p3,p4}=12;
//  p5..p8 need s1(T1) complete = drain 8 oldest -> vmcnt(4); leaves
//  p3,p4 = s0.B(T2), first needed at p8's gate. p8 symmetric (leaves
//  p7,p8 = s1.B(T3), needed next-p4). Prologue GATE4 (leaves s1.B(T1)),
//  peel p4 GATE0 (everything needed). 12-read phases get lgkmcnt(8)
//  pre-gate (template's smoothing).
// Clobber proofs: every STAGE issues after the previous phase's SECOND
// barrier, which follows the lgkm(0) that drained all waves' last reads
// of that region. Fresh-slot reads follow {gate; BAR; BAR} (m104).
// Stage map p1..p8: s1A.h0(T1) s1A.h1(T1) s0B.h0(T2) s0B.h1(T2)
//   s0A.h0(T2) s0A.h1(T2) s1B.h0(T3) s1B.h1(T3)
// Registers: acc 128 AGPR + aq 16 + bq 32 + addr ~35 -> fits 128 cap.
#define GBM 256
#define GBN 256

#define STAGE(s, mat, h, T) do {                                              \
    const unsigned short* _src = ((mat) ? pB : pA)                            \
        + (size_t)((h) * 128) * K + (size_t)(T) * 64;                         \
    char* _dst = ldsc + (s) * 65536 + (mat) * 32768 + (h) * 16384 + dOff;     \
    gload_lds16(_src, _dst);                                                  \
    gload_lds16(_src + (size_t)64 * K, _dst + 8192);                          \
} while (0)

#define RD_B(s) do {                                                          \
    _Pragma("unroll")                                                         \
    for (int ni = 0; ni < 4; ++ni)                                            \
        _Pragma("unroll")                                                     \
        for (int kk = 0; kk < 2; ++kk)                                        \
            bq[ni][kk] = *(const bf16x8*)(ldsc + (s) * 65536 + 32768          \
                + ((wc * 64 + ni * 16 + lrow) << 7) + ckk[kk]);               \
} while (0)

#define RD_A(q, s) do {                                                       \
    _Pragma("unroll")                                                         \
    for (int m2 = 0; m2 < 2; ++m2)                                            \
        _Pragma("unroll")                                                     \
        for (int kk = 0; kk < 2; ++kk)                                        \
            aq[m2][kk] = *(const bf16x8*)(ldsc + (s) * 65536                  \
                + ((wr * 128 + ((q) * 2 + m2) * 16 + lrow) << 7) + ckk[kk]);  \
} while (0)

// kk-OUTER: acc[q*2+m2][ni] reused only after 8 intervening MFMAs
#define MF(q) do {                                                            \
    __builtin_amdgcn_s_setprio(1);                                            \
    _Pragma("unroll")                                                         \
    for (int kk = 0; kk < 2; ++kk)                                            \
        _Pragma("unroll")                                                     \
        for (int m2 = 0; m2 < 2; ++m2)                                        \
            _Pragma("unroll")                                                 \
            for (int ni = 0; ni < 4; ++ni)                                    \
                acc[(q) * 2 + m2][ni] = __builtin_amdgcn_mfma_f32_16x16x32_bf16( \
                    aq[m2][kk], bq[ni][kk], acc[(q) * 2 + m2][ni], 0, 0, 0);  \
    __builtin_amdgcn_s_setprio(0);                                            \
} while (0)

#define LG do { asm volatile("s_waitcnt lgkmcnt(0)" ::: "memory");            \
                __builtin_amdgcn_sched_barrier(0); } while (0)
#define LGK8  asm volatile("s_waitcnt lgkmcnt(8)" ::: "memory")
#define BAR   asm volatile("s_barrier" ::: "memory")
#define GATE4 asm volatile("s_waitcnt vmcnt(4)" ::: "memory")
#define GATE0 asm volatile("s_waitcnt vmcnt(0)" ::: "memory")

template <int EPI>
__global__ __launch_bounds__(512, 2)
void gemm256(const unsigned short* __restrict__ A,
             const unsigned short* __restrict__ B,
             const float* __restrict__ bias_n,
             const float* __restrict__ resadd,
             void* __restrict__ Cout,
             int M, int N, int K) {
    __shared__ unsigned short lds[2][2][2][128 * 64];  // [slot][A/B][half][.]
    char* ldsc = (char*)&lds[0][0][0][0];
    const int tid = threadIdx.x;
    const int lane = tid & 63;
    const int w = tid >> 6;
    const int wr = w >> 2;   // 0..1
    const int wc = w & 3;    // 0..3

    const int nwg = gridDim.x;
    const int lg = (blockIdx.x & 7) * (nwg >> 3) + (blockIdx.x >> 3);
    const int nbx = N / GBN;
    const int brow = lg / nbx;
    const int bcol = lg % nbx;

    // staging source (pre-swizzled; zero-conflict formulas)
    const int srow = tid >> 3;                                   // 0..63
    const int scol = ((((tid & 7) << 4) ^ ((srow & 7) << 4)) >> 1);
    const unsigned short* pA = A + (size_t)(brow * GBM + srow) * K + scol;
    const unsigned short* pB = B + (size_t)(bcol * GBN + srow) * K + scol;
    const int dOff = tid * 16;

    // ds_read column bytes (zero measured conflicts)
    const int lrow = lane & 15;
    int ckk[2];
    ckk[0] = (((lane >> 4) << 4)) ^ ((lrow & 7) << 4);
    ckk[1] = ckk[0] ^ 64;

    f32x4 acc[8][4] = {};
    bf16x8 aq[2][2];   // phase-local A fragments [m2][kk]
    bf16x8 bq[4][2];   // per-tile B fragments (read at q0 phases)

    const int NT = K / 64;
    const int niter = NT / 2;

    // prologue: s0 full tile0 (8 loads) + s1.B of tile1 (4 loads);
    // GATE4 leaves s1.B in flight (p1 needs s0 only)
    STAGE(0, 1, 0, 0); STAGE(0, 1, 1, 0);
    STAGE(0, 0, 0, 0); STAGE(0, 0, 1, 0);
    STAGE(1, 1, 0, 1); STAGE(1, 1, 1, 1);
    GATE4;
    BAR;

    for (int i = 0; i < niter - 1; ++i) {
        const int T1 = 2 * i + 1, T2 = 2 * i + 2, T3 = 2 * i + 3;
        // p1 (q0, s0): 12 reads; lgkm(8) smoothing; stage s1A.h0(T1)
        RD_B(0); RD_A(0, 0); STAGE(1, 0, 0, T1); LGK8;  BAR; LG; MF(0); BAR;
        // p2
        RD_A(1, 0);          STAGE(1, 0, 1, T1);        BAR; LG; MF(1); BAR;
        // p3
        RD_A(2, 0);          STAGE(0, 1, 0, T2);        BAR; LG; MF(2); BAR;
        // p4: gate AFTER own stage -> vmcnt(4) drains prev-p7..p2 (s1 T1)
        RD_A(3, 0);          STAGE(0, 1, 1, T2); GATE4; BAR; LG; MF(3); BAR;
        // p5 (q0, s1)
        RD_B(1); RD_A(0, 1); STAGE(0, 0, 0, T2); LGK8;  BAR; LG; MF(0); BAR;
        // p6
        RD_A(1, 1);          STAGE(0, 0, 1, T2);        BAR; LG; MF(1); BAR;
        // p7
        RD_A(2, 1);          STAGE(1, 1, 0, T3);        BAR; LG; MF(2); BAR;
        // p8: vmcnt(4) drains p3..p6 (s0 T2); leaves p7,p8 (s1B T3)
        RD_A(3, 1);          STAGE(1, 1, 1, T3); GATE4; BAR; LG; MF(3); BAR;
    }
    {   // peeled last iteration (tiles NT-2 slot0, NT-1 slot1)
        const int T1 = NT - 1;
        RD_B(0); RD_A(0, 0); STAGE(1, 0, 0, T1); LGK8;  BAR; LG; MF(0); BAR;
        RD_A(1, 0);          STAGE(1, 0, 1, T1);        BAR; LG; MF(1); BAR;
        RD_A(2, 0);                                     BAR; LG; MF(2); BAR;
        RD_A(3, 0);                              GATE0; BAR; LG; MF(3); BAR;
        RD_B(1); RD_A(0, 1); LGK8;                      BAR; LG; MF(0); BAR;
        RD_A(1, 1);                                     BAR; LG; MF(1); BAR;
        RD_A(2, 1);                                     BAR; LG; MF(2); BAR;
        RD_A(3, 1);                                     BAR; LG; MF(3);
    }

    // epilogue: C/D layout col = lane&15, row = (lane>>4)*4 + j
    const int c0 = bcol * GBN + wc * 64 + lrow;
    const int r0 = brow * GBM + wr * 128 + (lane >> 4) * 4;
#pragma unroll
    for (int mi = 0; mi < 8; ++mi) {
#pragma unroll
        for (int j = 0; j < 4; ++j) {
            const int row = r0 + mi * 16 + j;
#pragma unroll
            for (int ni = 0; ni < 4; ++ni) {
                const int col = c0 + ni * 16;
                float x = acc[mi][ni][j] + bias_n[col];
                if (EPI == 0) {
                    ((unsigned short*)Cout)[(size_t)row * N + col] = f2bf(gelu_tanh(x));
                } else {
                    const size_t off = (size_t)row * N + col;
                    ((float*)Cout)[off] = x + resadd[off];
                }
            }
        }
    }
}

extern "C" void kernel_launch(void* const* d_in, const int* in_sizes, int n_in,
                              void* d_out, int out_size, void* d_ws, size_t ws_size,
                              hipStream_t stream) {
    const float* input    = (const float*)d_in[0];
    const float* residual = (const float*)d_in[1];
    const float* bias     = (const float*)d_in[2];
    const float* attn_nw  = (const float*)d_in[3];
    const float* attn_nb  = (const float*)d_in[4];
    const float* inter_w  = (const float*)d_in[5];
    const float* inter_b  = (const float*)d_in[6];
    const float* output_w = (const float*)d_in[7];
    const float* output_b = (const float*)d_in[8];

    const int H = in_sizes[3];            // 4096
    const int I = in_sizes[6];            // 16384
    const int T = in_sizes[0] / H;        // B*S = 4096

    char* ws = (char*)d_ws;
    float* resadd      = (float*)ws;
    unsigned short* ln = (unsigned short*)(ws + (size_t)T * H * 4);
    unsigned short* w1 = (unsigned short*)((char*)ln + (size_t)T * H * 2);
    unsigned short* w2 = w1 + (size_t)I * H;
    unsigned short* act = w2 + (size_t)H * I;

    fused_add_ln<<<T, 256, 0, stream>>>(input, residual, bias, attn_nw, attn_nb,
                                        resadd, ln, H);

    {
        long long n4 = (long long)I * H / 4;
        int blocks = (int)((n4 + 255) / 256);
        cast_w<<<blocks, 256, 0, stream>>>(inter_w, w1, n4);
        cast_w<<<blocks, 256, 0, stream>>>(output_w, w2, n4);
    }

    // GEMM1: act = gelu(ln @ inter_w^T + inter_b)   [T,I]
    {
        dim3 grid((T / GBM) * (I / GBN));
        gemm256<0><<<grid, 512, 0, stream>>>(ln, w1, inter_b, nullptr, act, T, I, H);
    }

    // GEMM2: out = act @ output_w^T + output_b + resadd   [T,H]
    {
        dim3 grid((T / GBM) * (H / GBN));
        gemm256<1><<<grid, 512, 0, stream>>>(act, w2, output_b, resadd, d_out, T, H, I);
    }
}

// Round 23
// 1093.812 us; speedup vs baseline: 1.0245x; 1.0245x over previous
//
#include <hip/hip_runtime.h>
#include <hip/hip_bf16.h>
#include <cstdint>
#include <math.h>

typedef __attribute__((ext_vector_type(4))) float f32x4;
typedef __attribute__((ext_vector_type(8))) __bf16 bf16x8;

__device__ __forceinline__ unsigned short f2bf(float f) {
    union { float f; unsigned u; } v; v.f = f;
    unsigned u = v.u + 0x7fffu + ((v.u >> 16) & 1u);
    return (unsigned short)(u >> 16);
}

__device__ __forceinline__ float gelu_tanh(float x) {
    float x3 = x * x * x;
    float t = tanhf(0.7978845608028654f * (x + 0.044715f * x3));
    return 0.5f * x * (1.0f + t);
}

__device__ __forceinline__ void gload_lds16(const void* g, void* l) {
    __builtin_amdgcn_global_load_lds(
        (__attribute__((address_space(1))) void*)(uintptr_t)g,
        (__attribute__((address_space(3))) void*)(unsigned)(uintptr_t)l,
        16, 0, 0);
}

// ---------------- fused bias-add + residual + LayerNorm ----------------
__global__ __launch_bounds__(256)
void fused_add_ln(const float* __restrict__ in, const float* __restrict__ res,
                  const float* __restrict__ bias, const float* __restrict__ nw,
                  const float* __restrict__ nb, float* __restrict__ resadd,
                  unsigned short* __restrict__ lnout, int H) {
    const int row = blockIdx.x;
    const int tid = threadIdx.x;
    const size_t base = (size_t)row * H;
    float v[16];
    float s = 0.f, ss = 0.f;
#pragma unroll
    for (int i = 0; i < 4; ++i) {
        int idx = (i * 256 + tid) * 4;
        float4 a = *(const float4*)(in + base + idx);
        float4 b = *(const float4*)(res + base + idx);
        float4 c = *(const float4*)(bias + idx);
        float x0 = a.x + b.x + c.x, x1 = a.y + b.y + c.y;
        float x2 = a.z + b.z + c.z, x3 = a.w + b.w + c.w;
        v[i * 4 + 0] = x0; v[i * 4 + 1] = x1; v[i * 4 + 2] = x2; v[i * 4 + 3] = x3;
        s += x0 + x1 + x2 + x3;
        ss += x0 * x0 + x1 * x1 + x2 * x2 + x3 * x3;
    }
#pragma unroll
    for (int off = 32; off > 0; off >>= 1) {
        s += __shfl_down(s, off);
        ss += __shfl_down(ss, off);
    }
    __shared__ float red[8];
    const int w = tid >> 6;
    if ((tid & 63) == 0) { red[w] = s; red[4 + w] = ss; }
    __syncthreads();
    s = red[0] + red[1] + red[2] + red[3];
    ss = red[4] + red[5] + red[6] + red[7];
    const float mean = s / H;
    const float var = ss / H - mean * mean;
    const float rstd = rsqrtf(var + 1e-12f);
#pragma unroll
    for (int i = 0; i < 4; ++i) {
        int idx = (i * 256 + tid) * 4;
        float4 wv = *(const float4*)(nw + idx);
        float4 bv = *(const float4*)(nb + idx);
        float4 r;
        r.x = v[i * 4 + 0]; r.y = v[i * 4 + 1]; r.z = v[i * 4 + 2]; r.w = v[i * 4 + 3];
        *(float4*)(resadd + base + idx) = r;
        ushort4 o;
        o.x = f2bf((r.x - mean) * rstd * wv.x + bv.x);
        o.y = f2bf((r.y - mean) * rstd * wv.y + bv.y);
        o.z = f2bf((r.z - mean) * rstd * wv.z + bv.z);
        o.w = f2bf((r.w - mean) * rstd * wv.w + bv.w);
        *(ushort4*)(lnout + base + idx) = o;
    }
}

// ---------------- fp32 -> bf16 weight cast ----------------
__global__ __launch_bounds__(256)
void cast_w(const float* __restrict__ w, unsigned short* __restrict__ o, long long n4) {
    long long i = (long long)blockIdx.x * 256 + threadIdx.x;
    if (i >= n4) return;
    float4 f = *(const float4*)(w + i * 4);
    ushort4 u;
    u.x = f2bf(f.x); u.y = f2bf(f.y); u.z = f2bf(f.z); u.w = f2bf(f.w);
    *(ushort4*)(o + i * 4) = u;
}

// ---- 256x256 bf16 GEMM, C = A*B^T: R17 FINAL (verified best of 14) -----
// 512 thr = 8 waves (2M x 4N), per-wave 128x64. LDS 128 KiB, slot = tile&1.
// Structure: single-barrier lockstep phases + B-prefetch at gate ends.
// Verified 3x: ~502-519us/GEMM, MfmaUtil 50-52%, 0 spill, 0 conflicts.
// Session laws (14 structural A/Bs):
//  - >48 fragment VGPRs live across barriers spills (128 arch cap: 512-thr
//    block => 256 unified/wave, acc = 128 AGPR); costs ~25% (R8/R12/R14/R18).
//  - Abandoning lockstep loses 3-7% (R9/R11); split/compiler waits lose
//    ~10% (R15/R16); double-barrier m201-style phases lose ~3% (R22);
//    barrier halving 16->8 won +2.3% (R13), further merging spills (R18).
//  - GATE2 is the TIGHTEST SAFE gate: it executes BEFORE p4's stage, so
//    in-flight = {prev-p7,prev-p8,p1,p2,p3}; leaving >2 exposes p2's
//    s1.A(T1).h1 (read at p5) -> R20's absmax 1.5 race. Deadline audits
//    must count from the gate's program position.
// Phase p: {RD_A(q) [+GATE2 @p4,p8]; BAR; STAGE 2 halves; lgkm(0)+schedbar;
//           setprio(1); 16 MFMA kk-outer; setprio(0); [RD_B @p4,p8 end]}
// Stage map p1..p8 (2 gloads each): s1A.h0(T1) s1A.h1(T1) s0B.h0(T2)
//   s0B.h1(T2) s0A.h0(T2) s0A.h1(T2) s1B.h0(T3) s1B.h1(T3)
#define GBM 256
#define GBN 256

#define STAGE(s, mat, h, T) do {                                              \
    const unsigned short* _src = ((mat) ? pB : pA)                            \
        + (size_t)((h) * 128) * K + (size_t)(T) * 64;                         \
    char* _dst = ldsc + (s) * 65536 + (mat) * 32768 + (h) * 16384 + dOff;     \
    gload_lds16(_src, _dst);                                                  \
    gload_lds16(_src + (size_t)64 * K, _dst + 8192);                          \
} while (0)

#define RD_B(s) do {                                                          \
    _Pragma("unroll")                                                         \
    for (int ni = 0; ni < 4; ++ni)                                            \
        _Pragma("unroll")                                                     \
        for (int kk = 0; kk < 2; ++kk)                                        \
            bq[ni][kk] = *(const bf16x8*)(ldsc + (s) * 65536 + 32768          \
                + ((wc * 64 + ni * 16 + lrow) << 7) + ckk[kk]);               \
} while (0)

#define RD_A(q, s) do {                                                       \
    _Pragma("unroll")                                                         \
    for (int m2 = 0; m2 < 2; ++m2)                                            \
        _Pragma("unroll")                                                     \
        for (int kk = 0; kk < 2; ++kk)                                        \
            aq[m2][kk] = *(const bf16x8*)(ldsc + (s) * 65536                  \
                + ((wr * 128 + ((q) * 2 + m2) * 16 + lrow) << 7) + ckk[kk]);  \
} while (0)

// kk-OUTER: acc[q*2+m2][ni] reused only after 8 intervening MFMAs
#define MF(q) do {                                                            \
    __builtin_amdgcn_s_setprio(1);                                            \
    _Pragma("unroll")                                                         \
    for (int kk = 0; kk < 2; ++kk)                                            \
        _Pragma("unroll")                                                     \
        for (int m2 = 0; m2 < 2; ++m2)                                        \
            _Pragma("unroll")                                                 \
            for (int ni = 0; ni < 4; ++ni)                                    \
                acc[(q) * 2 + m2][ni] = __builtin_amdgcn_mfma_f32_16x16x32_bf16( \
                    aq[m2][kk], bq[ni][kk], acc[(q) * 2 + m2][ni], 0, 0, 0);  \
    __builtin_amdgcn_s_setprio(0);                                            \
} while (0)

#define LG do { asm volatile("s_waitcnt lgkmcnt(0)" ::: "memory");            \
                __builtin_amdgcn_sched_barrier(0); } while (0)
#define BAR   asm volatile("s_barrier" ::: "memory")
#define GATE2 asm volatile("s_waitcnt vmcnt(2)" ::: "memory")
#define GATE4 asm volatile("s_waitcnt vmcnt(4)" ::: "memory")
#define GATE0 asm volatile("s_waitcnt vmcnt(0)" ::: "memory")

template <int EPI>
__global__ __launch_bounds__(512, 2)
void gemm256(const unsigned short* __restrict__ A,
             const unsigned short* __restrict__ B,
             const float* __restrict__ bias_n,
             const float* __restrict__ resadd,
             void* __restrict__ Cout,
             int M, int N, int K) {
    __shared__ unsigned short lds[2][2][2][128 * 64];  // [slot][A/B][half][.]
    char* ldsc = (char*)&lds[0][0][0][0];
    const int tid = threadIdx.x;
    const int lane = tid & 63;
    const int w = tid >> 6;
    const int wr = w >> 2;   // 0..1
    const int wc = w & 3;    // 0..3

    const int nwg = gridDim.x;
    const int lg = (blockIdx.x & 7) * (nwg >> 3) + (blockIdx.x >> 3);
    const int nbx = N / GBN;
    const int brow = lg / nbx;
    const int bcol = lg % nbx;

    // staging source (pre-swizzled; zero-conflict formulas)
    const int srow = tid >> 3;                                   // 0..63
    const int scol = ((((tid & 7) << 4) ^ ((srow & 7) << 4)) >> 1);
    const unsigned short* pA = A + (size_t)(brow * GBM + srow) * K + scol;
    const unsigned short* pB = B + (size_t)(bcol * GBN + srow) * K + scol;
    const int dOff = tid * 16;

    // ds_read column bytes (zero measured conflicts)
    const int lrow = lane & 15;
    int ckk[2];
    ckk[0] = (((lane >> 4) << 4)) ^ ((lrow & 7) << 4);
    ckk[1] = ckk[0] ^ 64;

    f32x4 acc[8][4] = {};
    bf16x8 aq[2][2];   // phase-local A fragments [m2][kk]
    bf16x8 bq[4][2];   // per-tile B fragments (prefetched at gate phases)

    const int NT = K / 64;
    const int niter = NT / 2;

    // prologue: s0 full tile0 + s1.B of tile1; gate leaves s1.B in flight;
    // pre-read B(tile0) after BAR (drained by p1's LG)
    STAGE(0, 1, 0, 0); STAGE(0, 1, 1, 0);
    STAGE(0, 0, 0, 0); STAGE(0, 0, 1, 0);
    STAGE(1, 1, 0, 1); STAGE(1, 1, 1, 1);
    GATE4;
    BAR;
    RD_B(0);

    for (int i = 0; i < niter - 1; ++i) {
        const int T1 = 2 * i + 1, T2 = 2 * i + 2, T3 = 2 * i + 3;
        RD_A(0, 0);                 BAR; STAGE(1, 0, 0, T1); LG; MF(0);            // p1
        RD_A(1, 0);                 BAR; STAGE(1, 0, 1, T1); LG; MF(1);            // p2
        RD_A(2, 0);                 BAR; STAGE(0, 1, 0, T2); LG; MF(2);            // p3
        RD_A(3, 0); GATE2;          BAR; STAGE(0, 1, 1, T2); LG; MF(3); RD_B(1);   // p4
        RD_A(0, 1);                 BAR; STAGE(0, 0, 0, T2); LG; MF(0);            // p5
        RD_A(1, 1);                 BAR; STAGE(0, 0, 1, T2); LG; MF(1);            // p6
        RD_A(2, 1);                 BAR; STAGE(1, 1, 0, T3); LG; MF(2);            // p7
        RD_A(3, 1); GATE2;          BAR; STAGE(1, 1, 1, T3); LG; MF(3); RD_B(0);   // p8
    }
    {   // peeled last iteration (tiles NT-2 slot0, NT-1 slot1)
        const int T1 = NT - 1;
        RD_A(0, 0);                 BAR; STAGE(1, 0, 0, T1); LG; MF(0);
        RD_A(1, 0);                 BAR; STAGE(1, 0, 1, T1); LG; MF(1);
        RD_A(2, 0);                 BAR;                     LG; MF(2);
        RD_A(3, 0); GATE0;          BAR;                     LG; MF(3); RD_B(1);
        RD_A(0, 1);                 BAR;                     LG; MF(0);
        RD_A(1, 1);                 BAR;                     LG; MF(1);
        RD_A(2, 1);                 BAR;                     LG; MF(2);
        RD_A(3, 1);                 BAR;                     LG; MF(3);
    }

    // epilogue: C/D layout col = lane&15, row = (lane>>4)*4 + j
    const int c0 = bcol * GBN + wc * 64 + lrow;
    const int r0 = brow * GBM + wr * 128 + (lane >> 4) * 4;
#pragma unroll
    for (int mi = 0; mi < 8; ++mi) {
#pragma unroll
        for (int j = 0; j < 4; ++j) {
            const int row = r0 + mi * 16 + j;
#pragma unroll
            for (int ni = 0; ni < 4; ++ni) {
                const int col = c0 + ni * 16;
                float x = acc[mi][ni][j] + bias_n[col];
                if (EPI == 0) {
                    ((unsigned short*)Cout)[(size_t)row * N + col] = f2bf(gelu_tanh(x));
                } else {
                    const size_t off = (size_t)row * N + col;
                    ((float*)Cout)[off] = x + resadd[off];
                }
            }
        }
    }
}

extern "C" void kernel_launch(void* const* d_in, const int* in_sizes, int n_in,
                              void* d_out, int out_size, void* d_ws, size_t ws_size,
                              hipStream_t stream) {
    const float* input    = (const float*)d_in[0];
    const float* residual = (const float*)d_in[1];
    const float* bias     = (const float*)d_in[2];
    const float* attn_nw  = (const float*)d_in[3];
    const float* attn_nb  = (const float*)d_in[4];
    const float* inter_w  = (const float*)d_in[5];
    const float* inter_b  = (const float*)d_in[6];
    const float* output_w = (const float*)d_in[7];
    const float* output_b = (const float*)d_in[8];

    const int H = in_sizes[3];            // 4096
    const int I = in_sizes[6];            // 16384
    const int T = in_sizes[0] / H;        // B*S = 4096

    char* ws = (char*)d_ws;
    float* resadd      = (float*)ws;
    unsigned short* ln = (unsigned short*)(ws + (size_t)T * H * 4);
    unsigned short* w1 = (unsigned short*)((char*)ln + (size_t)T * H * 2);
    unsigned short* w2 = w1 + (size_t)I * H;
    unsigned short* act = w2 + (size_t)H * I;

    fused_add_ln<<<T, 256, 0, stream>>>(input, residual, bias, attn_nw, attn_nb,
                                        resadd, ln, H);

    {
        long long n4 = (long long)I * H / 4;
        int blocks = (int)((n4 + 255) / 256);
        cast_w<<<blocks, 256, 0, stream>>>(inter_w, w1, n4);
        cast_w<<<blocks, 256, 0, stream>>>(output_w, w2, n4);
    }

    // GEMM1: act = gelu(ln @ inter_w^T + inter_b)   [T,I]
    {
        dim3 grid((T / GBM) * (I / GBN));
        gemm256<0><<<grid, 512, 0, stream>>>(ln, w1, inter_b, nullptr, act, T, I, H);
    }

    // GEMM2: out = act @ output_w^T + output_b + resadd   [T,H]
    {
        dim3 grid((T / GBM) * (H / GBN));
        gemm256<1><<<grid, 512, 0, stream>>>(act, w2, output_b, resadd, d_out, T, H, I);
    }
}